// Round 4
// baseline (102.144 us; speedup 1.0000x reference)
//
#include <hip/hip_runtime.h>
#include <cstddef>

#define PMOD 97
#define HID 512
#define NPAIR 9409
#define NSTEPS 15

typedef __attribute__((ext_vector_type(8))) short short8;
typedef __attribute__((ext_vector_type(4))) float f32x4;

static __device__ __forceinline__ unsigned short f2bf_rn(float f) {
    unsigned u = __float_as_uint(f);
    u += 0x7FFFu + ((u >> 16) & 1u);
    return (unsigned short)(u >> 16);
}
static __device__ __forceinline__ float bf2f(unsigned short h) {
    return __uint_as_float(((unsigned)h) << 16);
}

// ---------------------------------------------------------------------------
// k_w2: W2 f32 [97][512] -> w2hi/w2lo bf16 split
// ---------------------------------------------------------------------------
__global__ __launch_bounds__(256) void k_w2(const float* __restrict__ W2,
                                            short* __restrict__ w2hi,
                                            short* __restrict__ w2lo) {
    const int idx = blockIdx.x * 256 + threadIdx.x;     // per float4
    if (idx * 4 >= PMOD * HID) return;
    const float4 v = *reinterpret_cast<const float4*>(W2 + idx * 4);
    const float vv[4] = {v.x, v.y, v.z, v.w};
#pragma unroll
    for (int q = 0; q < 4; ++q) {
        const unsigned short hi = f2bf_rn(vv[q]);
        const unsigned short lo = f2bf_rn(vv[q] - bf2f(hi));
        w2hi[idx * 4 + q] = (short)hi;
        w2lo[idx * 4 + q] = (short)lo;
    }
}

// ---------------------------------------------------------------------------
// k_tr: W1 [512][1024] -> W1T [1024][512]  (LDS 64x64 tiles, coalesced)
// ---------------------------------------------------------------------------
__global__ __launch_bounds__(256) void k_tr(const float* __restrict__ W1,
                                            float* __restrict__ W1T) {
    __shared__ float tile[64][65];
    const int t = threadIdx.x;
    const int cIdx = blockIdx.x >> 3;      // 0..15 (col tile of W1)
    const int rIdx = blockIdx.x & 7;       // 0..7  (row tile of W1)
    const int r0 = rIdx * 64, c0 = cIdx * 64;

#pragma unroll
    for (int i = 0; i < 4; ++i) {
        const int flat4 = t + 256 * i;     // float4 units within 64x64
        const int r = flat4 >> 4;
        const int c4 = flat4 & 15;
        const float4 v = *reinterpret_cast<const float4*>(
            W1 + (size_t)(r0 + r) * 1024 + c0 + c4 * 4);
        tile[r][c4 * 4 + 0] = v.x;
        tile[r][c4 * 4 + 1] = v.y;
        tile[r][c4 * 4 + 2] = v.z;
        tile[r][c4 * 4 + 3] = v.w;
    }
    __syncthreads();
#pragma unroll
    for (int i = 0; i < 4; ++i) {
        const int flat4 = t + 256 * i;
        const int tc = flat4 >> 4;         // col within W1-tile = row of W1T-tile
        const int r4 = flat4 & 15;
        float4 ov;
        ov.x = tile[r4 * 4 + 0][tc];
        ov.y = tile[r4 * 4 + 1][tc];
        ov.z = tile[r4 * 4 + 2][tc];
        ov.w = tile[r4 * 4 + 3][tc];
        *reinterpret_cast<float4*>(W1T + (size_t)(c0 + tc) * 512 + r0 + r4 * 4) = ov;
    }
}

// ---------------------------------------------------------------------------
// k_ab: Ap[e][h] = b1[h] + sum_k embed[e][k] * W1T[k][h]
//       Bm[e][h] =         sum_k embed[e][k] * W1T[512+k][h]
// grid = 25 e-groups x 8 h-groups; block = 4 waves = 4 e's (wave-uniform e).
// W1T reads coalesced; embed reads wave-uniform (scalar path).
// ---------------------------------------------------------------------------
__global__ __launch_bounds__(256) void k_ab(const float* __restrict__ embed,
                                            const float* __restrict__ W1T,
                                            const float* __restrict__ b1,
                                            float* __restrict__ Ap,
                                            float* __restrict__ Bm) {
    const int t = threadIdx.x;
    const int lane = t & 63;
    const int eg = blockIdx.x / 8;
    const int hg = blockIdx.x - eg * 8;
    const int e = __builtin_amdgcn_readfirstlane(eg * 4 + (t >> 6));
    if (e >= PMOD) return;
    const int hcol = hg * 64 + lane;

    const float* __restrict__ erow = embed + (size_t)e * HID;
    const float* __restrict__ wa = W1T + hcol;
    const float* __restrict__ wb = W1T + (size_t)HID * HID + hcol;

    float accA = 0.f, accB = 0.f;
#pragma unroll 4
    for (int k = 0; k < HID; ++k) {
        const float ev = erow[k];
        accA = fmaf(ev, wa[(size_t)k * HID], accA);
        accB = fmaf(ev, wb[(size_t)k * HID], accB);
    }
    Ap[(size_t)e * HID + hcol] = accA + b1[hcol];
    Bm[(size_t)e * HID + hcol] = accB;
}

// ---------------------------------------------------------------------------
// k_pairs: fused LIF sim + MFMA GEMM.
// Block = 256 thr = 4 waves = 2 m-tiles (32 pairs) x 2 k-halves.
// Wave (mi,kh): lane sims pair m = base+mi*16+(lane&15), h-slice
// kt*32+(lane>>4)*8 for kt in its k-half; wspk -> bf16 hi/lo a-frags in LDS.
// GEMM: 7 n-tiles x 8 kt x {hi*hi, lo*hi, hi*lo} MFMA. kh partial sums
// reduced through LDS; kh==0 stores pairOut + b2*S.
// ---------------------------------------------------------------------------
__global__ __launch_bounds__(256) void k_pairs(const float* __restrict__ Ap,
                                               const float* __restrict__ Bm,
                                               const short* __restrict__ w2hi,
                                               const short* __restrict__ w2lo,
                                               const float* __restrict__ b2,
                                               const float* __restrict__ pbeta1,
                                               const float* __restrict__ pbeta2,
                                               const float* __restrict__ pthr1,
                                               float* __restrict__ pairOut) {
    __shared__ char lds[65536];   // [4 waves][8 kt][64 lanes][16B] hi, then lo at +32KB

    const float beta1 = fminf(fmaxf(pbeta1[0], 0.1f), 0.9f);
    const float beta2 = fminf(fmaxf(pbeta2[0], 0.1f), 0.9f);
    const float thr   = fmaxf(pthr1[0], 0.1f);

    const int t = threadIdx.x;
    const int lane = t & 63;
    const int w = t >> 6;          // wave id
    const int mi = w >> 1;         // m-tile within block
    const int kh = w & 1;          // k-half
    const int pblk = blockIdx.x * 32;

    const int pid0 = pblk + mi * 16 + (lane & 15);
    const int pid  = (pid0 < NPAIR) ? pid0 : (NPAIR - 1);
    const unsigned i = (unsigned)pid / PMOD;
    const unsigned j = (unsigned)pid - i * PMOD;
    const int koff = (lane >> 4) * 8;

    // ---- phase 1: simulate, write a-frags ----
    for (int kt = 0; kt < 8; ++kt) {
        const int h = (kh * 8 + kt) * 32 + koff;
        const float* ap = Ap + (size_t)i * HID + h;
        const float* bp = Bm + (size_t)j * HID + h;
        const float4 a0 = *reinterpret_cast<const float4*>(ap);
        const float4 a1 = *reinterpret_cast<const float4*>(ap + 4);
        const float4 g0 = *reinterpret_cast<const float4*>(bp);
        const float4 g1 = *reinterpret_cast<const float4*>(bp + 4);
        float c[8] = {a0.x + g0.x, a0.y + g0.y, a0.z + g0.z, a0.w + g0.w,
                      a1.x + g1.x, a1.y + g1.y, a1.z + g1.z, a1.w + g1.w};
        float cm[8], m[8], sp[8], wv[8];
#pragma unroll
        for (int q = 0; q < 8; ++q) {
            cm[q] = c[q] - thr; m[q] = 0.f; sp[q] = 0.f; wv[q] = 0.f;
        }
        for (int s = 0; s < NSTEPS; ++s) {
#pragma unroll
            for (int q = 0; q < 8; ++q) {
                const float cadj = (sp[q] != 0.f) ? cm[q] : c[q];
                m[q] = fmaf(beta1, m[q], cadj);
                sp[q] = (m[q] > thr) ? 1.f : 0.f;
                wv[q] = fmaf(beta2, wv[q], sp[q]);
            }
        }
        short8 hv, lv;
#pragma unroll
        for (int q = 0; q < 8; ++q) {
            const unsigned short hb = f2bf_rn(wv[q]);
            hv[q] = (short)hb;
            lv[q] = (short)f2bf_rn(wv[q] - bf2f(hb));
        }
        const int slot = ((w * 8 + kt) * 64 + lane) * 16;
        *reinterpret_cast<short8*>(lds + slot)         = hv;
        *reinterpret_cast<short8*>(lds + 32768 + slot) = lv;
    }

    // ---- phase 2: MFMA GEMM over this wave's k-half ----
    f32x4 acc[7];
#pragma unroll
    for (int nt = 0; nt < 7; ++nt) acc[nt] = (f32x4){0.f, 0.f, 0.f, 0.f};

    for (int kt = 0; kt < 8; ++kt) {
        const int slot = ((w * 8 + kt) * 64 + lane) * 16;
        const short8 ahi = *reinterpret_cast<const short8*>(lds + slot);
        const short8 alo = *reinterpret_cast<const short8*>(lds + 32768 + slot);
        const int hb = (kh * 8 + kt) * 32 + koff;
#pragma unroll
        for (int nt = 0; nt < 7; ++nt) {
            const int o = nt * 16 + (lane & 15);
            const int oc = (o < PMOD) ? o : (PMOD - 1);
            const short8 bhi = *reinterpret_cast<const short8*>(w2hi + (size_t)oc * HID + hb);
            const short8 blo = *reinterpret_cast<const short8*>(w2lo + (size_t)oc * HID + hb);
            acc[nt] = __builtin_amdgcn_mfma_f32_16x16x32_bf16(ahi, bhi, acc[nt], 0, 0, 0);
            acc[nt] = __builtin_amdgcn_mfma_f32_16x16x32_bf16(alo, bhi, acc[nt], 0, 0, 0);
            acc[nt] = __builtin_amdgcn_mfma_f32_16x16x32_bf16(ahi, blo, acc[nt], 0, 0, 0);
        }
    }

    // ---- reduce k-halves through LDS (reuse a-frag region) ----
    __syncthreads();
    if (kh == 1) {
#pragma unroll
        for (int nt = 0; nt < 7; ++nt) {
            *reinterpret_cast<f32x4*>(lds + ((mi * 7 + nt) * 64 + lane) * 16) = acc[nt];
        }
    }
    __syncthreads();
    if (kh == 0) {
        float S = 0.f;
#pragma unroll
        for (int s = 0; s < NSTEPS; ++s) S = fmaf(beta2, S, 1.f);
#pragma unroll
        for (int nt = 0; nt < 7; ++nt) {
            const f32x4 part = *reinterpret_cast<const f32x4*>(
                lds + ((mi * 7 + nt) * 64 + lane) * 16);
            const int o = nt * 16 + (lane & 15);
            if (o < PMOD) {
                const float bias = b2[o] * S;
#pragma unroll
                for (int reg = 0; reg < 4; ++reg) {
                    const int prow = pblk + mi * 16 + (lane >> 4) * 4 + reg;
                    if (prow < NPAIR) {
                        pairOut[(size_t)prow * PMOD + o] = acc[nt][reg] + part[reg] + bias;
                    }
                }
            }
        }
    }
}

// ---------------------------------------------------------------------------
// k_scatter: out[b][o] = pairOut[x[b,0]*97 + x[b,1]][o]
// ---------------------------------------------------------------------------
__global__ __launch_bounds__(256) void k_scatter(const int* __restrict__ x,
                                                 const float* __restrict__ pairOut,
                                                 float* __restrict__ out,
                                                 int total) {
    const unsigned idx = blockIdx.x * 256u + threadIdx.x;
    if (idx >= (unsigned)total) return;
    const unsigned b = idx / PMOD;
    const unsigned o = idx - b * PMOD;
    const int pid = x[2 * b] * PMOD + x[2 * b + 1];
    out[idx] = pairOut[(size_t)pid * PMOD + o];
}

// ---------------------------------------------------------------------------
extern "C" void kernel_launch(void* const* d_in, const int* in_sizes, int n_in,
                              void* d_out, int out_size, void* d_ws, size_t ws_size,
                              hipStream_t stream) {
    const int*   x     = (const int*)d_in[0];
    const float* embed = (const float*)d_in[1];
    const float* W1    = (const float*)d_in[2];
    const float* b1    = (const float*)d_in[3];
    const float* W2    = (const float*)d_in[4];
    const float* b2    = (const float*)d_in[5];
    const float* beta1 = (const float*)d_in[6];
    const float* beta2 = (const float*)d_in[7];
    const float* thr1  = (const float*)d_in[8];

    float* out = (float*)d_out;
    const int B = in_sizes[0] / 2;

    // ws layout: [0, 3.65MB): union { W1T (2MB, dead after k_ab), pairOut }
    //            then Ap, Bm, w2hi, w2lo.
    char* ws = (char*)d_ws;
    float* W1T     = (float*)ws;                      // 1024*512*4 = 2 MB
    float* pairOut = (float*)ws;                      // 9409*97*4 = 3.65 MB (after k_ab)
    float* Ap      = (float*)(ws + 3655680);          // 97*512*4 = 198,656 B
    float* Bm      = (float*)(ws + 3854336);
    short* w2hi    = (short*)(ws + 4052992);          // 97*512*2 = 99,328 B
    short* w2lo    = (short*)(ws + 4152320);

    k_w2<<<49, 256, 0, stream>>>(W2, w2hi, w2lo);
    k_tr<<<128, 256, 0, stream>>>(W1, W1T);
    k_ab<<<200, 256, 0, stream>>>(embed, W1T, b1, Ap, Bm);

    const int nblk = (NPAIR + 31) / 32;   // 295 blocks, 32 pairs each
    k_pairs<<<nblk, 256, 0, stream>>>(Ap, Bm, w2hi, w2lo, b2, beta1, beta2, thr1, pairOut);

    const int total = B * PMOD;
    k_scatter<<<(total + 255) / 256, 256, 0, stream>>>(x, pairOut, out, total);
}

// Round 5
// 48.870 us; speedup vs baseline: 2.0901x; 2.0901x over previous
//
#include <hip/hip_runtime.h>
#include <cstddef>

#define PMOD 97
#define HID 512
#define NPAIR 9409
#define NSTEPS 15

typedef __attribute__((ext_vector_type(8))) short short8;
typedef __attribute__((ext_vector_type(4))) short short4_t;
typedef __attribute__((ext_vector_type(4))) float f32x4;

static __device__ __forceinline__ unsigned short f2bf_rn(float f) {
    unsigned u = __float_as_uint(f);
    u += 0x7FFFu + ((u >> 16) & 1u);
    return (unsigned short)(u >> 16);
}
static __device__ __forceinline__ float bf2f(unsigned short h) {
    return __uint_as_float(((unsigned)h) << 16);
}

// ---------------------------------------------------------------------------
// k_cvt: W1 [512][1024] -> w1hi/w1lo bf16 ; embed [97][512] -> ehi/elo ;
//        W2 [97][512] -> w2bf (single bf16, round-nearest).
// One float4 per thread. Segments: W1 131072 f4, emb 12416 f4, W2 12416 f4.
// ---------------------------------------------------------------------------
__global__ __launch_bounds__(256) void k_cvt(const float* __restrict__ W1,
                                             const float* __restrict__ embed,
                                             const float* __restrict__ W2,
                                             short* __restrict__ w1hi,
                                             short* __restrict__ w1lo,
                                             short* __restrict__ ehi,
                                             short* __restrict__ elo,
                                             short* __restrict__ w2bf) {
    const int idx = blockIdx.x * 256 + threadIdx.x;
    if (idx < 131072) {
        const float4 v = ((const float4*)W1)[idx];
        const float vv[4] = {v.x, v.y, v.z, v.w};
        short4_t h4, l4;
#pragma unroll
        for (int q = 0; q < 4; ++q) {
            const unsigned short hb = f2bf_rn(vv[q]);
            h4[q] = (short)hb;
            l4[q] = (short)f2bf_rn(vv[q] - bf2f(hb));
        }
        *(short4_t*)(w1hi + idx * 4) = h4;
        *(short4_t*)(w1lo + idx * 4) = l4;
    } else if (idx < 143488) {
        const int k = idx - 131072;
        const float4 v = ((const float4*)embed)[k];
        const float vv[4] = {v.x, v.y, v.z, v.w};
        short4_t h4, l4;
#pragma unroll
        for (int q = 0; q < 4; ++q) {
            const unsigned short hb = f2bf_rn(vv[q]);
            h4[q] = (short)hb;
            l4[q] = (short)f2bf_rn(vv[q] - bf2f(hb));
        }
        *(short4_t*)(ehi + k * 4) = h4;
        *(short4_t*)(elo + k * 4) = l4;
    } else if (idx < 155904) {
        const int k = idx - 143488;
        const float4 v = ((const float4*)W2)[k];
        const float vv[4] = {v.x, v.y, v.z, v.w};
        short4_t h4;
#pragma unroll
        for (int q = 0; q < 4; ++q) h4[q] = (short)f2bf_rn(vv[q]);
        *(short4_t*)(w2bf + k * 4) = h4;
    }
}

// ---------------------------------------------------------------------------
// k_abm: MFMA GEMM  cur1-parts = emb @ W1^T, split into
//   Ap[e][h] = b1[h] + sum_{k<512} emb[e][k]   * W1[h][k]
//   Bm[e][h] =         sum_{k<512} emb[e][k]   * W1[h][512+k]
// treated as one GEMM with N=1024 (n<512 -> Ap, n>=512 -> Bm).
// hi/lo 3-pass bf16 (error ~5e-6 on cur1). Grid = 7 mt x 16 ng, 4 waves =
// 4 k-quarters, LDS reduce.
// ---------------------------------------------------------------------------
__global__ __launch_bounds__(256) void k_abm(const short* __restrict__ ehi,
                                             const short* __restrict__ elo,
                                             const short* __restrict__ w1hi,
                                             const short* __restrict__ w1lo,
                                             const float* __restrict__ b1,
                                             float* __restrict__ Ap,
                                             float* __restrict__ Bm) {
    __shared__ f32x4 red[3][4][64];   // 12 KB

    const int t = threadIdx.x;
    const int lane = t & 63;
    const int kq = t >> 6;
    const int mt = blockIdx.x >> 4;      // 0..6
    const int ng = blockIdx.x & 15;      // 0..15

    int e = mt * 16 + (lane & 15);
    if (e > PMOD - 1) e = PMOD - 1;
    const int kbase = kq * 128 + (lane >> 4) * 8;

    f32x4 acc[4];
#pragma unroll
    for (int nt = 0; nt < 4; ++nt) acc[nt] = (f32x4){0.f, 0.f, 0.f, 0.f};

#pragma unroll
    for (int kt = 0; kt < 4; ++kt) {
        const int k = kbase + kt * 32;
        const short8 ahi = *(const short8*)(ehi + (size_t)e * HID + k);
        const short8 alo = *(const short8*)(elo + (size_t)e * HID + k);
#pragma unroll
        for (int nt = 0; nt < 4; ++nt) {
            const int n = ng * 64 + nt * 16 + (lane & 15);   // 0..1023
            const int h = n & 511;
            const int half = n >> 9;
            const size_t boff = (size_t)h * 1024 + half * HID + k;
            const short8 bhi = *(const short8*)(w1hi + boff);
            const short8 blo = *(const short8*)(w1lo + boff);
            acc[nt] = __builtin_amdgcn_mfma_f32_16x16x32_bf16(ahi, bhi, acc[nt], 0, 0, 0);
            acc[nt] = __builtin_amdgcn_mfma_f32_16x16x32_bf16(alo, bhi, acc[nt], 0, 0, 0);
            acc[nt] = __builtin_amdgcn_mfma_f32_16x16x32_bf16(ahi, blo, acc[nt], 0, 0, 0);
        }
    }

    if (kq != 0) {
#pragma unroll
        for (int nt = 0; nt < 4; ++nt) red[kq - 1][nt][lane] = acc[nt];
    }
    __syncthreads();
    if (kq == 0) {
#pragma unroll
        for (int nt = 0; nt < 4; ++nt) {
            f32x4 a = acc[nt];
            a += red[0][nt][lane];
            a += red[1][nt][lane];
            a += red[2][nt][lane];
            const int n = ng * 64 + nt * 16 + (lane & 15);
            const int h = n & 511;
            const int half = n >> 9;
            const float bias = half ? 0.f : b1[h];
#pragma unroll
            for (int reg = 0; reg < 4; ++reg) {
                const int er = mt * 16 + (lane >> 4) * 4 + reg;
                if (er < PMOD) {
                    if (half == 0) Ap[(size_t)er * HID + h] = a[reg] + bias;
                    else           Bm[(size_t)er * HID + h] = a[reg];
                }
            }
        }
    }
}

// ---------------------------------------------------------------------------
// k_pairs v3: 589 blocks x 4 waves. Wave = k-quarter (128 h).
// Lane sims pair m=lane&15 (pid=blk*16+m), h-slice (lane>>4)*8 within each
// kt; wspk kept in REGISTERS -> bf16 -> MFMA A-operand directly.
// Single-pass bf16 GEMM vs w2bf. LDS only for 4-way k-reduce (21.5 KB).
// ---------------------------------------------------------------------------
__global__ __launch_bounds__(256) void k_pairs(const float* __restrict__ Ap,
                                               const float* __restrict__ Bm,
                                               const short* __restrict__ w2bf,
                                               const float* __restrict__ b2,
                                               const float* __restrict__ pbeta1,
                                               const float* __restrict__ pbeta2,
                                               const float* __restrict__ pthr1,
                                               float* __restrict__ pairOut) {
    __shared__ f32x4 red[3][7][64];   // 21,504 B

    const float beta1 = fminf(fmaxf(pbeta1[0], 0.1f), 0.9f);
    const float beta2 = fminf(fmaxf(pbeta2[0], 0.1f), 0.9f);
    const float thr   = fmaxf(pthr1[0], 0.1f);

    const int t = threadIdx.x;
    const int lane = t & 63;
    const int kq = t >> 6;
    const int pblk = blockIdx.x * 16;

    const int pid0 = pblk + (lane & 15);
    const int pid  = (pid0 < NPAIR) ? pid0 : (NPAIR - 1);
    const unsigned i = (unsigned)pid / PMOD;
    const unsigned j = (unsigned)pid - i * PMOD;
    const int kbase = kq * 128 + (lane >> 4) * 8;

    f32x4 acc[7];
#pragma unroll
    for (int nt = 0; nt < 7; ++nt) acc[nt] = (f32x4){0.f, 0.f, 0.f, 0.f};

#pragma unroll
    for (int kt = 0; kt < 4; ++kt) {
        const int k = kbase + kt * 32;
        const float* ap = Ap + (size_t)i * HID + k;
        const float* bp = Bm + (size_t)j * HID + k;
        const float4 a0 = *(const float4*)ap;
        const float4 a1 = *(const float4*)(ap + 4);
        const float4 g0 = *(const float4*)bp;
        const float4 g1 = *(const float4*)(bp + 4);
        float c[8] = {a0.x + g0.x, a0.y + g0.y, a0.z + g0.z, a0.w + g0.w,
                      a1.x + g1.x, a1.y + g1.y, a1.z + g1.z, a1.w + g1.w};
        float cm[8], m[8], w[8];
        bool sb[8];
#pragma unroll
        for (int q = 0; q < 8; ++q) {
            cm[q] = c[q] - thr; m[q] = 0.f; w[q] = 0.f; sb[q] = false;
        }
        for (int s = 0; s < NSTEPS; ++s) {
#pragma unroll
            for (int q = 0; q < 8; ++q) {
                const float cadj = sb[q] ? cm[q] : c[q];
                m[q] = fmaf(beta1, m[q], cadj);
                sb[q] = m[q] > thr;
                w[q] = fmaf(beta2, w[q], sb[q] ? 1.f : 0.f);
            }
        }
        short8 af;
#pragma unroll
        for (int q = 0; q < 8; ++q) af[q] = (short)f2bf_rn(w[q]);

#pragma unroll
        for (int nt = 0; nt < 7; ++nt) {
            const int o0 = nt * 16 + (lane & 15);
            const int oc = (o0 < PMOD) ? o0 : (PMOD - 1);
            const short8 bf = *(const short8*)(w2bf + (size_t)oc * HID + k);
            acc[nt] = __builtin_amdgcn_mfma_f32_16x16x32_bf16(af, bf, acc[nt], 0, 0, 0);
        }
    }

    if (kq != 0) {
#pragma unroll
        for (int nt = 0; nt < 7; ++nt) red[kq - 1][nt][lane] = acc[nt];
    }
    __syncthreads();
    if (kq == 0) {
        float S = 0.f;
#pragma unroll
        for (int s = 0; s < NSTEPS; ++s) S = fmaf(beta2, S, 1.f);
#pragma unroll
        for (int nt = 0; nt < 7; ++nt) {
            f32x4 a = acc[nt];
            a += red[0][nt][lane];
            a += red[1][nt][lane];
            a += red[2][nt][lane];
            const int o = nt * 16 + (lane & 15);
            if (o < PMOD) {
                const float bias = b2[o] * S;
#pragma unroll
                for (int reg = 0; reg < 4; ++reg) {
                    const int prow = pblk + (lane >> 4) * 4 + reg;
                    if (prow < NPAIR)
                        pairOut[(size_t)prow * PMOD + o] = a[reg] + bias;
                }
            }
        }
    }
}

// ---------------------------------------------------------------------------
// k_scatter: out[b][o] = pairOut[x[b,0]*97 + x[b,1]][o]
// ---------------------------------------------------------------------------
__global__ __launch_bounds__(256) void k_scatter(const int* __restrict__ x,
                                                 const float* __restrict__ pairOut,
                                                 float* __restrict__ out,
                                                 int total) {
    const unsigned idx = blockIdx.x * 256u + threadIdx.x;
    if (idx >= (unsigned)total) return;
    const unsigned b = idx / PMOD;
    const unsigned o = idx - b * PMOD;
    const int pid = x[2 * b] * PMOD + x[2 * b + 1];
    out[idx] = pairOut[(size_t)pid * PMOD + o];
}

// ---------------------------------------------------------------------------
extern "C" void kernel_launch(void* const* d_in, const int* in_sizes, int n_in,
                              void* d_out, int out_size, void* d_ws, size_t ws_size,
                              hipStream_t stream) {
    const int*   x     = (const int*)d_in[0];
    const float* embed = (const float*)d_in[1];
    const float* W1    = (const float*)d_in[2];
    const float* b1    = (const float*)d_in[3];
    const float* W2    = (const float*)d_in[4];
    const float* b2    = (const float*)d_in[5];
    const float* beta1 = (const float*)d_in[6];
    const float* beta2 = (const float*)d_in[7];
    const float* thr1  = (const float*)d_in[8];

    float* out = (float*)d_out;
    const int B = in_sizes[0] / 2;

    // ws layout (total 4,147,456 B — less than R4's proven 4.25 MB usage):
    //   [0, 3,650,816): union { w1hi(1MB) w1lo(1MB) ehi(97KB) elo(97KB) — dead
    //                           after k_abm | pairOut (3.65MB, k_pairs onward) }
    //   3,650,816: w2bf (99,328)
    //   3,750,144: Ap   (198,656)
    //   3,948,800: Bm   (198,656)
    char* ws = (char*)d_ws;
    short* w1hi    = (short*)(ws);
    short* w1lo    = (short*)(ws + 1048576);
    short* ehi     = (short*)(ws + 2097152);
    short* elo     = (short*)(ws + 2196480);
    float* pairOut = (float*)(ws);
    short* w2bf    = (short*)(ws + 3650816);
    float* Ap      = (float*)(ws + 3750144);
    float* Bm      = (float*)(ws + 3948800);

    k_cvt<<<609, 256, 0, stream>>>(W1, embed, W2, w1hi, w1lo, ehi, elo, w2bf);

    k_abm<<<112, 256, 0, stream>>>(ehi, elo, w1hi, w1lo, b1, Ap, Bm);

    const int nblk = (NPAIR + 15) / 16;   // 589 blocks
    k_pairs<<<nblk, 256, 0, stream>>>(Ap, Bm, w2bf, b2, beta1, beta2, thr1, pairOut);

    const int total = B * PMOD;
    k_scatter<<<(total + 255) / 256, 256, 0, stream>>>(x, pairOut, out, total);
}

// Round 6
// 46.270 us; speedup vs baseline: 2.2075x; 1.0562x over previous
//
#include <hip/hip_runtime.h>
#include <cstddef>

#define PMOD 97
#define HID 512
#define NPAIR 9409
#define NSTEPS 15

typedef __attribute__((ext_vector_type(8))) short short8;
typedef __attribute__((ext_vector_type(4))) short short4_t;
typedef __attribute__((ext_vector_type(4))) float f32x4;

static __device__ __forceinline__ unsigned short f2bf_rn(float f) {
    unsigned u = __float_as_uint(f);
    u += 0x7FFFu + ((u >> 16) & 1u);
    return (unsigned short)(u >> 16);
}
static __device__ __forceinline__ float bf2f(unsigned short h) {
    return __uint_as_float(((unsigned)h) << 16);
}
// load 8 f32, produce bf16 hi + residual-lo frags
static __device__ __forceinline__ void split_hilo(const float* __restrict__ p,
                                                  short8& hi, short8& lo) {
    const float4 v0 = *(const float4*)p;
    const float4 v1 = *(const float4*)(p + 4);
    const float vv[8] = {v0.x, v0.y, v0.z, v0.w, v1.x, v1.y, v1.z, v1.w};
#pragma unroll
    for (int q = 0; q < 8; ++q) {
        const unsigned short hb = f2bf_rn(vv[q]);
        hi[q] = (short)hb;
        lo[q] = (short)f2bf_rn(vv[q] - bf2f(hb));
    }
}

// ---------------------------------------------------------------------------
// k_abm: fused convert + MFMA GEMM for cur1 parts.
//   prologue (grid-stride): W2 f32 -> w2bf bf16 (used by k_pairs only).
//   main: one GEMM emb[97x512] @ W1^T with N=1024 (n<512 -> Ap + b1, else Bm),
//   hi/lo 3-pass bf16, converts emb/W1 on the fly (each element read once
//   per block). Grid = 7 mt x 64 ng = 448 blocks; 4 waves = 4 k-quarters.
// ---------------------------------------------------------------------------
__global__ __launch_bounds__(256) void k_abm(const float* __restrict__ embed,
                                             const float* __restrict__ W1,
                                             const float* __restrict__ W2,
                                             const float* __restrict__ b1,
                                             short* __restrict__ w2bf,
                                             float* __restrict__ Ap,
                                             float* __restrict__ Bm) {
    __shared__ f32x4 red[3][64];   // 3 KB

    const int t = threadIdx.x;
    const int lane = t & 63;
    const int kq = t >> 6;

    // ---- W2 convert (blocks 0..48 cover all 12416 float4's) ----
    const int gid = blockIdx.x * 256 + t;
    if (gid < PMOD * HID / 4) {
        const float4 v = ((const float4*)W2)[gid];
        const float vv[4] = {v.x, v.y, v.z, v.w};
        short4_t h4;
#pragma unroll
        for (int q = 0; q < 4; ++q) h4[q] = (short)f2bf_rn(vv[q]);
        *(short4_t*)(w2bf + gid * 4) = h4;
    }

    // ---- GEMM ----
    const int mt = blockIdx.x >> 6;      // 0..6
    const int ng = blockIdx.x & 63;      // 0..63
    int e = mt * 16 + (lane & 15);
    if (e > PMOD - 1) e = PMOD - 1;
    const int n = ng * 16 + (lane & 15); // 0..1023
    const int h = n & 511;
    const int half = n >> 9;
    const int kbase = kq * 128 + (lane >> 4) * 8;

    f32x4 acc = (f32x4){0.f, 0.f, 0.f, 0.f};
#pragma unroll
    for (int kt = 0; kt < 4; ++kt) {
        const int k = kbase + kt * 32;
        short8 ahi, alo, bhi, blo;
        split_hilo(embed + (size_t)e * HID + k, ahi, alo);
        split_hilo(W1 + (size_t)h * 1024 + half * HID + k, bhi, blo);
        acc = __builtin_amdgcn_mfma_f32_16x16x32_bf16(ahi, bhi, acc, 0, 0, 0);
        acc = __builtin_amdgcn_mfma_f32_16x16x32_bf16(alo, bhi, acc, 0, 0, 0);
        acc = __builtin_amdgcn_mfma_f32_16x16x32_bf16(ahi, blo, acc, 0, 0, 0);
    }

    if (kq != 0) red[kq - 1][lane] = acc;
    __syncthreads();
    if (kq == 0) {
        acc += red[0][lane];
        acc += red[1][lane];
        acc += red[2][lane];
        const float bias = half ? 0.f : b1[h];
#pragma unroll
        for (int reg = 0; reg < 4; ++reg) {
            const int er = mt * 16 + (lane >> 4) * 4 + reg;
            if (er < PMOD) {
                if (half == 0) Ap[(size_t)er * HID + h] = acc[reg] + bias;
                else           Bm[(size_t)er * HID + h] = acc[reg];
            }
        }
    }
}

// ---------------------------------------------------------------------------
// k_pairs v4: 589 blocks x 8 waves (512 thr).
//   sim phase: wave w sims k-tiles {2w, 2w+1}: lane owns pair m=lane&15,
//   h = kt*32 + (lane>>4)*8; 15 LIF steps in registers; wspk -> bf16 frag
//   published to LDS wfrag[kt][lane] (consecutive 16B/lane, conflict-free;
//   layout IS the MFMA A-frag at the same lane).
//   GEMM phase: wave = (kq = w&3, nh = w>>2); kq covers 4 k-tiles, nh covers
//   n-tiles 0..3 / 4..6. LDS reduce over kq; kq==0 stores pairOut + b2*S.
// ---------------------------------------------------------------------------
__global__ __launch_bounds__(512) void k_pairs(const float* __restrict__ Ap,
                                               const float* __restrict__ Bm,
                                               const short* __restrict__ w2bf,
                                               const float* __restrict__ b2,
                                               const float* __restrict__ pbeta1,
                                               const float* __restrict__ pbeta2,
                                               const float* __restrict__ pthr1,
                                               float* __restrict__ pairOut) {
    __shared__ short8 wfrag[16][64];      // 16 KB
    __shared__ f32x4 red[2][3][4][64];    // 24 KB

    const float beta1 = fminf(fmaxf(pbeta1[0], 0.1f), 0.9f);
    const float beta2 = fminf(fmaxf(pbeta2[0], 0.1f), 0.9f);
    const float thr   = fmaxf(pthr1[0], 0.1f);

    const int t = threadIdx.x;
    const int lane = t & 63;
    const int w = t >> 6;                 // 0..7
    const int pblk = blockIdx.x * 16;

    const int pid0 = pblk + (lane & 15);
    const int pid  = (pid0 < NPAIR) ? pid0 : (NPAIR - 1);
    const unsigned i = (unsigned)pid / PMOD;
    const unsigned j = (unsigned)pid - i * PMOD;

    // ---- sim phase ----
#pragma unroll
    for (int kk = 0; kk < 2; ++kk) {
        const int kt = 2 * w + kk;
        const int h = kt * 32 + (lane >> 4) * 8;
        const float* ap = Ap + (size_t)i * HID + h;
        const float* bp = Bm + (size_t)j * HID + h;
        const float4 a0 = *(const float4*)ap;
        const float4 a1 = *(const float4*)(ap + 4);
        const float4 g0 = *(const float4*)bp;
        const float4 g1 = *(const float4*)(bp + 4);
        float c[8] = {a0.x + g0.x, a0.y + g0.y, a0.z + g0.z, a0.w + g0.w,
                      a1.x + g1.x, a1.y + g1.y, a1.z + g1.z, a1.w + g1.w};
        float cm[8], m[8], wv[8];
        bool sb[8];
#pragma unroll
        for (int q = 0; q < 8; ++q) {
            cm[q] = c[q] - thr; m[q] = 0.f; wv[q] = 0.f; sb[q] = false;
        }
        for (int s = 0; s < NSTEPS; ++s) {
#pragma unroll
            for (int q = 0; q < 8; ++q) {
                const float cadj = sb[q] ? cm[q] : c[q];
                m[q] = fmaf(beta1, m[q], cadj);
                sb[q] = m[q] > thr;
                wv[q] = fmaf(beta2, wv[q], sb[q] ? 1.f : 0.f);
            }
        }
        short8 af;
#pragma unroll
        for (int q = 0; q < 8; ++q) af[q] = (short)f2bf_rn(wv[q]);
        wfrag[kt][lane] = af;
    }
    __syncthreads();

    // ---- GEMM phase ----
    const int kq = w & 3;
    const int nh = w >> 2;
    const int ntb = nh * 4;               // 0 or 4

    f32x4 acc[4];
#pragma unroll
    for (int q = 0; q < 4; ++q) acc[q] = (f32x4){0.f, 0.f, 0.f, 0.f};

#pragma unroll
    for (int kk = 0; kk < 4; ++kk) {
        const int kt = kq * 4 + kk;
        const short8 af = wfrag[kt][lane];
        const int k = kt * 32 + (lane >> 4) * 8;
#pragma unroll
        for (int q = 0; q < 4; ++q) {
            const int nt = ntb + q;
            if (nt < 7) {
                const int o0 = nt * 16 + (lane & 15);
                const int oc = (o0 < PMOD) ? o0 : (PMOD - 1);
                const short8 bf = *(const short8*)(w2bf + (size_t)oc * HID + k);
                acc[q] = __builtin_amdgcn_mfma_f32_16x16x32_bf16(af, bf, acc[q], 0, 0, 0);
            }
        }
    }

    if (kq != 0) {
#pragma unroll
        for (int q = 0; q < 4; ++q)
            if (ntb + q < 7) red[nh][kq - 1][q][lane] = acc[q];
    }
    __syncthreads();
    if (kq == 0) {
        float S = 0.f;
#pragma unroll
        for (int s = 0; s < NSTEPS; ++s) S = fmaf(beta2, S, 1.f);
#pragma unroll
        for (int q = 0; q < 4; ++q) {
            const int nt = ntb + q;
            if (nt < 7) {
                f32x4 a = acc[q];
                a += red[nh][0][q][lane];
                a += red[nh][1][q][lane];
                a += red[nh][2][q][lane];
                const int o = nt * 16 + (lane & 15);
                if (o < PMOD) {
                    const float bias = b2[o] * S;
#pragma unroll
                    for (int reg = 0; reg < 4; ++reg) {
                        const int prow = pblk + (lane >> 4) * 4 + reg;
                        if (prow < NPAIR)
                            pairOut[(size_t)prow * PMOD + o] = a[reg] + bias;
                    }
                }
            }
        }
    }
}

// ---------------------------------------------------------------------------
// k_scatter: out[b][o] = pairOut[x[b,0]*97 + x[b,1]][o]
// ---------------------------------------------------------------------------
__global__ __launch_bounds__(256) void k_scatter(const int* __restrict__ x,
                                                 const float* __restrict__ pairOut,
                                                 float* __restrict__ out,
                                                 int total) {
    const unsigned idx = blockIdx.x * 256u + threadIdx.x;
    if (idx >= (unsigned)total) return;
    const unsigned b = idx / PMOD;
    const unsigned o = idx - b * PMOD;
    const int pid = x[2 * b] * PMOD + x[2 * b + 1];
    out[idx] = pairOut[(size_t)pid * PMOD + o];
}

// ---------------------------------------------------------------------------
extern "C" void kernel_launch(void* const* d_in, const int* in_sizes, int n_in,
                              void* d_out, int out_size, void* d_ws, size_t ws_size,
                              hipStream_t stream) {
    const int*   x     = (const int*)d_in[0];
    const float* embed = (const float*)d_in[1];
    const float* W1    = (const float*)d_in[2];
    const float* b1    = (const float*)d_in[3];
    const float* W2    = (const float*)d_in[4];
    const float* b2    = (const float*)d_in[5];
    const float* beta1 = (const float*)d_in[6];
    const float* beta2 = (const float*)d_in[7];
    const float* thr1  = (const float*)d_in[8];

    float* out = (float*)d_out;
    const int B = in_sizes[0] / 2;

    // ws layout (4,147,456 B total — same footprint as R5):
    //   0:         pairOut (9409*97*4 = 3,650,816)
    //   3,650,816: w2bf    (97*512*2 =    99,328)
    //   3,750,144: Ap      (97*512*4 =   198,656)
    //   3,948,800: Bm      (97*512*4 =   198,656)
    char* ws = (char*)d_ws;
    float* pairOut = (float*)(ws);
    short* w2bf    = (short*)(ws + 3650816);
    float* Ap      = (float*)(ws + 3750144);
    float* Bm      = (float*)(ws + 3948800);

    k_abm<<<448, 256, 0, stream>>>(embed, W1, W2, b1, w2bf, Ap, Bm);

    const int nblk = (NPAIR + 15) / 16;   // 589 blocks x 8 waves
    k_pairs<<<nblk, 512, 0, stream>>>(Ap, Bm, w2bf, b2, beta1, beta2, thr1, pairOut);

    const int total = B * PMOD;
    k_scatter<<<(total + 255) / 256, 256, 0, stream>>>(x, pairOut, out, total);
}